// Round 1
// baseline (313.408 us; speedup 1.0000x reference)
//
#include <hip/hip_runtime.h>
#include <hip/hip_bf16.h>

// ModulatedConv2d: B=16, C_in=C_out=128, H=W=128, K=3, S=512. fp32 I/O.
// Compute: bf16 MFMA (16x16x32), fp32 accumulate.
//
// R5: h-pair blocks (128co x 2h x 128w per block, 512 thr / 8 waves).
//  - Xs: 4 full image rows (h0-1..h0+2), bf16 swizzled, staged ONCE per block
//    (vs 3 restages before). No pad rows; w-edges via clamp+select-zero.
//  - Ws: 32 KB per tap via global_load_lds (amortized over 2 h rows).
//  - LDS 160 KB exactly -> 1 block/CU, 2 waves/SIMD.
//  - Bijective XCD-chunk swizzle (grid 1024 % 8 == 0) for x-row / wsW L2 reuse.

#define Bn 16
#define Cc 128
#define HW 128
#define Sv 512

typedef __bf16 bf16x8 __attribute__((ext_vector_type(8)));
typedef float f32x4 __attribute__((ext_vector_type(4)));
typedef unsigned short ushort8 __attribute__((ext_vector_type(8)));

static __device__ __forceinline__ unsigned short bf16bits(float f) {
    return __builtin_bit_cast(unsigned short, __float2bfloat16(f));
}

static __device__ __forceinline__ void gl_lds16(const void* g, void* l) {
    __builtin_amdgcn_global_load_lds(
        (const __attribute__((address_space(1))) unsigned int*)g,
        (__attribute__((address_space(3))) unsigned int*)l, 16, 0, 0);
}

// ---------------- kernel 1: s[b][ci] = style[b,:] . mod_w[ci,:] + mod_b[ci]
__global__ __launch_bounds__(64) void k_style(const float* __restrict__ style,
                                              const float* __restrict__ mod_w,
                                              const float* __restrict__ mod_b,
                                              float* __restrict__ s_out) {
    int b = blockIdx.x >> 7, ci = blockIdx.x & 127;
    int lane = threadIdx.x;
    const float* st = style + (size_t)b * Sv;
    const float* mw = mod_w + (size_t)ci * Sv;
    float acc = 0.f;
#pragma unroll
    for (int k = 0; k < Sv; k += 64)
        acc += st[k + lane] * mw[k + lane];
#pragma unroll
    for (int off = 32; off > 0; off >>= 1)
        acc += __shfl_down(acc, off, 64);
    if (lane == 0) s_out[b * Cc + ci] = acc + mod_b[ci];
}

// ---------------- kernel 2: modulate + demodulate (fp32), store bf16 PRE-SWIZZLED
// wsW[b][j][co][ pos ]  where pos(content ci) = (((ci>>3) ^ (co&7))<<3) + (ci&7)
__global__ __launch_bounds__(128) void k_mod(const float* __restrict__ weight,
                                             const float* __restrict__ s,
                                             __hip_bfloat16* __restrict__ wsW) {
    int b = blockIdx.x >> 7;
    int co = blockIdx.x & 127;
    int ci = threadIdx.x;
    float sv = s[b * Cc + ci];
    const float* wp = weight + ((size_t)co * Cc + ci) * 9;
    float wv[9];
    float ss = 0.f;
#pragma unroll
    for (int j = 0; j < 9; j++) {
        wv[j] = wp[j] * sv;
        ss += wv[j] * wv[j];
    }
    __shared__ float red[128];
    red[ci] = ss;
    __syncthreads();
    for (int s2 = 64; s2 > 0; s2 >>= 1) {
        if (ci < s2) red[ci] += red[ci + s2];
        __syncthreads();
    }
    float dec = rsqrtf(red[0] + 1e-8f);
    int pos = ((((ci >> 3) ^ (co & 7)) << 3) | (ci & 7));
#pragma unroll
    for (int j = 0; j < 9; j++) {
        wsW[(((size_t)b * 9 + j) * Cc + co) * Cc + pos] = __float2bfloat16(wv[j] * dec);
    }
}

// ---------------- kernel 3: implicit-GEMM conv via MFMA, h-pair blocks
// block = (b, h0=2*bh). 8 waves: (m2=co-half, th=h-row, n2=w-half), 64x64 tiles.
// Xs[j] holds image row h0-1+j (j=0..3), row w content ci at
//   w*128 + (((ci>>3) ^ (w&7))<<3) + (ci&7); OOB image rows zero-filled.
// Ws: verbatim global_load_lds image of pre-swizzled wsW (one tap at a time).
__global__ __launch_bounds__(512, 2) void k_conv(const float* __restrict__ x,
                                                 const __hip_bfloat16* __restrict__ wsW,
                                                 float* __restrict__ out) {
    __shared__ __align__(16) __bf16 Xs[4 * 128 * 128];  // 128 KB
    __shared__ __align__(16) __bf16 Ws[128 * 128];      // 32 KB  -> 160 KB total

    int bx0 = blockIdx.x;
    int bx = (bx0 & 7) * 128 + (bx0 >> 3);  // XCD-chunk swizzle, bijective (1024%8==0)
    int b = bx >> 6;
    int h0 = (bx & 63) << 1;

    int t = threadIdx.x;
    int lane = t & 63;
    int wv = t >> 6;         // 0..7
    int m2 = wv >> 2;        // co half
    int th = (wv >> 1) & 1;  // h row within pair
    int n2 = wv & 1;         // w half
    int l15 = lane & 15, quad = lane >> 4;

    f32x4 acc[4][4] = {};

    const float* xb = x + (size_t)b * (Cc * HW * HW);
    const __hip_bfloat16* wbase = wsW + (size_t)b * 9 * (Cc * Cc);

    // ---- stage 4 image rows (h0-1 .. h0+2) ONCE per block ----
    // item id: w = id&127 (lanes->consecutive w: coalesced loads, conflict-min writes)
    for (int j = 0; j < 4; j++) {
        int hp = h0 - 1 + j;
        bool ok = (unsigned)hp < (unsigned)HW;  // block-uniform
        const float* xr = xb + (size_t)hp * HW;
#pragma unroll
        for (int c = 0; c < 4; c++) {
            int id = c * 512 + t;
            int w = id & 127;
            int g = id >> 7;  // ci-group 0..15
            ushort8 pk = {};
            if (ok) {
                const float* p = xr + (size_t)g * 8 * (HW * HW) + w;
#pragma unroll
                for (int e = 0; e < 8; e++)
                    pk[e] = bf16bits(p[(size_t)e * (HW * HW)]);
            }
            *(bf16x8*)(&Xs[j * 16384 + w * 128 + ((g ^ (w & 7)) << 3)]) =
                __builtin_bit_cast(bf16x8, pk);
        }
    }

    for (int kh = 0; kh < 3; kh++) {
        int xbuf = (kh + th) * 16384;  // wave's image row = h0 + th + kh - 1
        for (int kw = 0; kw < 3; kw++) {
            __syncthreads();  // prior tap's Ws reads done; (first tap) orders Xs writes
            const __hip_bfloat16* wsrc = wbase + (size_t)(kh * 3 + kw) * (Cc * Cc);
#pragma unroll
            for (int c = 0; c < 4; c++) {
                int chunk = wv * 4 + c;  // 32 chunks of 1 KB
                gl_lds16(wsrc + chunk * 512 + lane * 8, &Ws[chunk * 512]);
            }
            __syncthreads();  // drains vmcnt -> Ws visible
#pragma unroll
            for (int ks = 0; ks < 4; ks++) {
                int kg = ks * 4 + quad;  // k0 = kg*8
                bf16x8 a[4], bb[4];
#pragma unroll
                for (int mi = 0; mi < 4; mi++) {
                    int co = m2 * 64 + mi * 16 + l15;
                    a[mi] = *(const bf16x8*)(&Ws[co * 128 + ((kg ^ (co & 7)) << 3)]);
                }
#pragma unroll
                for (int ni = 0; ni < 4; ni++) {
                    int xr = n2 * 64 + ni * 16 + l15 + kw - 1;  // x-col
                    int xrc = min(127, max(0, xr));
                    bf16x8 v = *(const bf16x8*)(
                        &Xs[xbuf + xrc * 128 + ((kg ^ (xrc & 7)) << 3)]);
                    if (xr != xrc) v = (bf16x8){};  // w-edge zero (per-lane cndmask)
                    bb[ni] = v;
                }
#pragma unroll
                for (int mi = 0; mi < 4; mi++)
#pragma unroll
                    for (int ni = 0; ni < 4; ni++)
                        acc[mi][ni] = __builtin_amdgcn_mfma_f32_16x16x32_bf16(
                            a[mi], bb[ni], acc[mi][ni], 0, 0, 0);
            }
        }
    }

    // epilogue: co = m2*64 + mi*16 + quad*4 + r, w = n2*64 + ni*16 + l15, h = h0+th
    int h = h0 + th;
    float* ob = out + (size_t)b * (Cc * HW * HW) + (size_t)h * HW;
#pragma unroll
    for (int mi = 0; mi < 4; mi++) {
#pragma unroll
        for (int ni = 0; ni < 4; ni++) {
            int w = n2 * 64 + ni * 16 + l15;
#pragma unroll
            for (int r = 0; r < 4; r++) {
                int co = m2 * 64 + mi * 16 + quad * 4 + r;
                ob[(size_t)co * (HW * HW) + w] = acc[mi][ni][r];
            }
        }
    }
}

extern "C" void kernel_launch(void* const* d_in, const int* in_sizes, int n_in,
                              void* d_out, int out_size, void* d_ws, size_t ws_size,
                              hipStream_t stream) {
    const float* x      = (const float*)d_in[0];
    const float* style  = (const float*)d_in[1];
    const float* weight = (const float*)d_in[2];
    const float* mod_w  = (const float*)d_in[3];
    const float* mod_b  = (const float*)d_in[4];
    float* out = (float*)d_out;

    // workspace: s (fp32, 8KB) | wsW (bf16, 4.72MB)
    float* s_ws = (float*)d_ws;
    __hip_bfloat16* wsW = (__hip_bfloat16*)((char*)d_ws + 8192);

    k_style<<<Bn * Cc, 64, 0, stream>>>(style, mod_w, mod_b, s_ws);
    k_mod<<<Bn * Cc, 128, 0, stream>>>(weight, s_ws, wsW);
    k_conv<<<Bn * (HW / 2), 512, 0, stream>>>(x, wsW, out);
}

// Round 2
// 302.332 us; speedup vs baseline: 1.0366x; 1.0366x over previous
//
#include <hip/hip_runtime.h>
#include <hip/hip_bf16.h>

// ModulatedConv2d: B=16, C_in=C_out=128, H=W=128, K=3, S=512. fp32 I/O.
// Compute: bf16 MFMA (16x16x32), fp32 accumulate.
//
// R6: barrier-free tap loop. Weights are stored by k_mod in MFMA-fragment
// order (1 KB lane-contiguous fragments), so k_conv loads A straight from
// global (L2-resident) into registers -- no Ws in LDS, no per-tap barriers.
// Exactly ONE __syncthreads per block (after Xs staging). LDS = 128 KB.
//  - h-pair blocks: 128co x 2h x 128w, 512 thr / 8 waves (64x64 tiles).
//  - Xs: 4 image rows (h0-1..h0+2), bf16 swizzled, staged once; w-edge by
//    clamp+select-zero.
//  - Bijective XCD-chunk swizzle (grid 1024 % 8 == 0): each XCD owns 2 b's
//    -> wsW working set 576 KB per XCD L2.

#define Bn 16
#define Cc 128
#define HW 128
#define Sv 512

typedef __bf16 bf16x8 __attribute__((ext_vector_type(8)));
typedef float f32x4 __attribute__((ext_vector_type(4)));
typedef unsigned short ushort8 __attribute__((ext_vector_type(8)));

static __device__ __forceinline__ unsigned short bf16bits(float f) {
    return __builtin_bit_cast(unsigned short, __float2bfloat16(f));
}

// ---------------- kernel 1: s[b][ci] = style[b,:] . mod_w[ci,:] + mod_b[ci]
__global__ __launch_bounds__(64) void k_style(const float* __restrict__ style,
                                              const float* __restrict__ mod_w,
                                              const float* __restrict__ mod_b,
                                              float* __restrict__ s_out) {
    int b = blockIdx.x >> 7, ci = blockIdx.x & 127;
    int lane = threadIdx.x;
    const float* st = style + (size_t)b * Sv;
    const float* mw = mod_w + (size_t)ci * Sv;
    float acc = 0.f;
#pragma unroll
    for (int k = 0; k < Sv; k += 64)
        acc += st[k + lane] * mw[k + lane];
#pragma unroll
    for (int off = 32; off > 0; off >>= 1)
        acc += __shfl_down(acc, off, 64);
    if (lane == 0) s_out[b * Cc + ci] = acc + mod_b[ci];
}

// ---------------- kernel 2: modulate + demodulate (fp32), store bf16 in
// MFMA-FRAGMENT order:
//   wsW[((b*9 + j)*32 + frag)*512 + lane*8 + e]
//   frag = (co>>6)*16 + ((co>>4)&3)*4 + (ci>>5)      (m2*16 + mi*4 + ks)
//   lane = ((ci>>3)&3)*16 + (co&15)                  (quad*16 + l15)
//   e    = ci&7
// so that in k_conv, lane l's bf16x8 at (frag, l) holds
//   A[co = m2*64+mi*16+(l&15)][k = (ks*4+(l>>4))*8 .. +7]
__global__ __launch_bounds__(128) void k_mod(const float* __restrict__ weight,
                                             const float* __restrict__ s,
                                             __hip_bfloat16* __restrict__ wsW) {
    int b = blockIdx.x >> 7;
    int co = blockIdx.x & 127;
    int ci = threadIdx.x;
    float sv = s[b * Cc + ci];
    const float* wp = weight + ((size_t)co * Cc + ci) * 9;
    float wv[9];
    float ss = 0.f;
#pragma unroll
    for (int j = 0; j < 9; j++) {
        wv[j] = wp[j] * sv;
        ss += wv[j] * wv[j];
    }
    __shared__ float red[128];
    red[ci] = ss;
    __syncthreads();
    for (int s2 = 64; s2 > 0; s2 >>= 1) {
        if (ci < s2) red[ci] += red[ci + s2];
        __syncthreads();
    }
    float dec = rsqrtf(red[0] + 1e-8f);
    int frag = ((co >> 6) << 4) | (((co >> 4) & 3) << 2) | (ci >> 5);
    int lane = (((ci >> 3) & 3) << 4) | (co & 15);
    int e = ci & 7;
#pragma unroll
    for (int j = 0; j < 9; j++) {
        wsW[(((size_t)b * 9 + j) * 32 + frag) * 512 + lane * 8 + e] =
            __float2bfloat16(wv[j] * dec);
    }
}

// ---------------- kernel 3: implicit-GEMM conv via MFMA, h-pair blocks,
// barrier-free tap loop (A from global registers, B from LDS Xs).
__global__ __launch_bounds__(512, 2) void k_conv(const float* __restrict__ x,
                                                 const __hip_bfloat16* __restrict__ wsW,
                                                 float* __restrict__ out) {
    __shared__ __align__(16) __bf16 Xs[4 * 128 * 128];  // 128 KB

    int bx0 = blockIdx.x;
    int bx = (bx0 & 7) * 128 + (bx0 >> 3);  // XCD-chunk swizzle, bijective (1024%8==0)
    int b = bx >> 6;
    int h0 = (bx & 63) << 1;

    int t = threadIdx.x;
    int lane = t & 63;
    int wv = t >> 6;         // 0..7
    int m2 = wv >> 2;        // co half
    int th = (wv >> 1) & 1;  // h row within pair
    int n2 = wv & 1;         // w half
    int l15 = lane & 15, quad = lane >> 4;

    f32x4 acc[4][4] = {};

    const float* xb = x + (size_t)b * (Cc * HW * HW);

    // ---- stage 4 image rows (h0-1 .. h0+2) ONCE per block ----
    // item id: w = id&127 (lanes->consecutive w: coalesced loads)
    // Xs elem (row=w, ci) at  w*128 + (((ci>>3) ^ (w&7))<<3) + (ci&7)
    for (int j = 0; j < 4; j++) {
        int hp = h0 - 1 + j;
        bool ok = (unsigned)hp < (unsigned)HW;  // block-uniform
        const float* xr = xb + (size_t)hp * HW;
#pragma unroll
        for (int c = 0; c < 4; c++) {
            int id = c * 512 + t;
            int w = id & 127;
            int g = id >> 7;  // ci-group 0..15
            ushort8 pk = {};
            if (ok) {
                const float* p = xr + (size_t)g * 8 * (HW * HW) + w;
#pragma unroll
                for (int e = 0; e < 8; e++)
                    pk[e] = bf16bits(p[(size_t)e * (HW * HW)]);
            }
            *(bf16x8*)(&Xs[j * 16384 + w * 128 + ((g ^ (w & 7)) << 3)]) =
                __builtin_bit_cast(bf16x8, pk);
        }
    }
    __syncthreads();  // the ONLY block barrier

    // A-fragment base for this wave's co-half
    const __hip_bfloat16* wb2 =
        wsW + ((size_t)b * 9) * (32 * 512) + (size_t)(m2 * 16) * 512 + lane * 8;

#pragma unroll
    for (int kh = 0; kh < 3; kh++) {
        int xbuf = (kh + th) * 16384;  // wave's image row = h0 + th + kh - 1
#pragma unroll
        for (int kw = 0; kw < 3; kw++) {
            const __hip_bfloat16* af = wb2 + (size_t)(kh * 3 + kw) * (32 * 512);
            // load all 16 A-fragments for this tap (ks-major: first-needed first)
            bf16x8 a[4][4];  // [ks][mi]
#pragma unroll
            for (int ks = 0; ks < 4; ks++)
#pragma unroll
                for (int mi = 0; mi < 4; mi++)
                    a[ks][mi] = *(const bf16x8*)(af + (size_t)(mi * 4 + ks) * 512);
#pragma unroll
            for (int ks = 0; ks < 4; ks++) {
                int kg = ks * 4 + quad;  // k0 = kg*8
                bf16x8 bb[4];
#pragma unroll
                for (int ni = 0; ni < 4; ni++) {
                    int xr = n2 * 64 + ni * 16 + l15 + kw - 1;  // x-col
                    int xrc = min(127, max(0, xr));
                    bf16x8 v = *(const bf16x8*)(
                        &Xs[xbuf + xrc * 128 + ((kg ^ (xrc & 7)) << 3)]);
                    if (xr != xrc) v = (bf16x8){};  // w-edge zero (per-lane cndmask)
                    bb[ni] = v;
                }
#pragma unroll
                for (int mi = 0; mi < 4; mi++)
#pragma unroll
                    for (int ni = 0; ni < 4; ni++)
                        acc[mi][ni] = __builtin_amdgcn_mfma_f32_16x16x32_bf16(
                            a[ks][mi], bb[ni], acc[mi][ni], 0, 0, 0);
            }
        }
    }

    // epilogue: co = m2*64 + mi*16 + quad*4 + r, w = n2*64 + ni*16 + l15, h = h0+th
    int h = h0 + th;
    float* ob = out + (size_t)b * (Cc * HW * HW) + (size_t)h * HW;
#pragma unroll
    for (int mi = 0; mi < 4; mi++) {
#pragma unroll
        for (int ni = 0; ni < 4; ni++) {
            int w = n2 * 64 + ni * 16 + l15;
#pragma unroll
            for (int r = 0; r < 4; r++) {
                int co = m2 * 64 + mi * 16 + quad * 4 + r;
                ob[(size_t)co * (HW * HW) + w] = acc[mi][ni][r];
            }
        }
    }
}

extern "C" void kernel_launch(void* const* d_in, const int* in_sizes, int n_in,
                              void* d_out, int out_size, void* d_ws, size_t ws_size,
                              hipStream_t stream) {
    const float* x      = (const float*)d_in[0];
    const float* style  = (const float*)d_in[1];
    const float* weight = (const float*)d_in[2];
    const float* mod_w  = (const float*)d_in[3];
    const float* mod_b  = (const float*)d_in[4];
    float* out = (float*)d_out;

    // workspace: s (fp32, 8KB) | wsW (bf16 fragment-order, 4.72MB)
    float* s_ws = (float*)d_ws;
    __hip_bfloat16* wsW = (__hip_bfloat16*)((char*)d_ws + 8192);

    k_style<<<Bn * Cc, 64, 0, stream>>>(style, mod_w, mod_b, s_ws);
    k_mod<<<Bn * Cc, 128, 0, stream>>>(weight, s_ws, wsW);
    k_conv<<<Bn * (HW / 2), 512, 0, stream>>>(x, wsW, out);
}